// Round 9
// baseline (703.511 us; speedup 1.0000x reference)
//
#include <hip/hip_runtime.h>
#include <hip/hip_bf16.h>
#include <math.h>

// Problem constants
#define B_    64
#define MAXT  511
#define TP1   512
#define S_    1024
#define H_    4096
#define M_TOTAL (B_*TP1)   // 32768 rows
#define NITER (S_/32)      // 32 K-iterations

typedef __attribute__((ext_vector_type(8))) short  short8;   // 8 bf16 = 4 VGPRs
typedef __attribute__((ext_vector_type(4))) short  short4v;  // 4 bf16 = 2 VGPRs
typedef __attribute__((ext_vector_type(4))) float  float4v;  // MFMA C/D frag

// ---- workspace layout (bytes) ----
// zbuf [0, 512KB); W1T past it. (No Sb buffer anymore -- A converts in-GEMM.)
#define ZBUF_BYTES ((size_t)M_TOTAL*4*sizeof(float))   // 524288
#define W1T_OFF    0x81000                             // 528384 >= ZBUF_BYTES

static __device__ __forceinline__ unsigned short f2bf(float f) {
    unsigned int u = __float_as_uint(f);
    u = u + 0x7fffu + ((u >> 16) & 1u);   // round-to-nearest-even
    return (unsigned short)(u >> 16);
}

static __device__ __forceinline__ short8 pack8(float4v lo, float4v hi) {
    short8 o;
    o[0] = (short)f2bf(lo[0]); o[1] = (short)f2bf(lo[1]);
    o[2] = (short)f2bf(lo[2]); o[3] = (short)f2bf(lo[3]);
    o[4] = (short)f2bf(hi[0]); o[5] = (short)f2bf(hi[1]);
    o[6] = (short)f2bf(hi[2]); o[7] = (short)f2bf(hi[3]);
    return o;
}

// ---- pre-pass: W1 (S x H fp32) -> W1T (H x S bf16), 64x64 LDS transpose ----
// (R7-verified.) Only 16 MB read / 8 MB write -- ~5 us. The old s->bf16 pass
// (134 MB read + 67 MB write, ~100 us) is gone: GEMM reads s fp32 directly.
__global__ __launch_bounds__(256) void prep_kernel(const float* __restrict__ W1,
                                                   unsigned short* __restrict__ W1T) {
    __shared__ float tile[64][65];                   // [k][h], +1 pad
    int tb = blockIdx.x;                             // 0..1023
    int h0 = (tb & 63) * 64;                         // H/64 = 64
    int k0 = (tb >> 6) * 64;                         // S/64 = 16
    int fx = threadIdx.x & 15;
    int r  = threadIdx.x >> 4;
    for (int rr = r; rr < 64; rr += 16) {
        float4v v = __builtin_nontemporal_load(
            (const float4v*)(W1 + (size_t)(k0 + rr) * H_ + h0 + fx * 4));
        tile[rr][fx*4+0] = v[0]; tile[rr][fx*4+1] = v[1];
        tile[rr][fx*4+2] = v[2]; tile[rr][fx*4+3] = v[3];
    }
    __syncthreads();
    int c4 = threadIdx.x & 15;
    int hr = threadIdx.x >> 4;
    for (int hh = hr; hh < 64; hh += 16) {
        short4v o;
        o[0] = (short)f2bf(tile[c4*4+0][hh]);
        o[1] = (short)f2bf(tile[c4*4+1][hh]);
        o[2] = (short)f2bf(tile[c4*4+2][hh]);
        o[3] = (short)f2bf(tile[c4*4+3][hh]);
        *(short4v*)(W1T + (size_t)(h0 + hh) * S_ + k0 + c4 * 4) = o;
    }
}

// ---- main fused GEMM ----
// 128x128 tile, BK=32, 4 waves 2x2 (64x64/wave, 16 MFMA/wave/iter -- the R7
// 8-wave shape regressed: fewer MFMAs/wave-chain + 1.5x LDS reads + 2x atomics).
// A: fp32 loaded straight from s, cvt->bf16 in-register, ds_write to LDS
//    (2 NAMED sets, distance-2; no vmcnt drain at barriers).
// B: NO LDS -- fragments load directly from W1T global (16x64B segments,
//    L2-served), distance-1 named double-buffer bfE/bfO.
// 2-level XCD swizzle: xcd=id&7 owns mtiles [32x,32x+32); within an XCD,
// work proceeds in (4 mtile x 8 ntile) groups: A group (2 MB fp32) + B band
// (2 MB bf16) fit the 4 MB XCD L2; s+W1T (~142 MB) are L3-resident.
__global__ __launch_bounds__(256, 3) void gemm_fused_kernel(
        const float* __restrict__ s,              // M x S fp32 (read direct!)
        const unsigned short* __restrict__ W1T,   // H x S bf16
        const float* __restrict__ b1,             // H
        const float* __restrict__ W2,             // H x 32 fp32 (cols 0..3 used)
        const int*   __restrict__ lengths,        // B
        float*       __restrict__ zbuf)           // M x 4
{
    int id   = blockIdx.x;
    int xcd  = id & 7;
    int r    = id >> 3;                  // 0..1023
    int grp  = r >> 5;                   // 0..31 : (mgrp fast, ngrp slow)
    int w    = r & 31;
    int mtile = xcd * 32 + (grp & 7) * 4 + (w >> 3);   // 0..255
    int ntile = (grp >> 3) * 8 + (w & 7);              // 0..31

    int b  = mtile >> 2;
    int t0 = (mtile & 3) * 128;
    if (lengths[b] <= t0) return;        // whole tile masked out

    int m0 = mtile * 128;
    int n0 = ntile * 128;

    __shared__ unsigned short smemA[2 * 128 * 32];   // 2 x 8 KB (A only)

    int tid  = threadIdx.x;
    int wid  = tid >> 6;
    int lane = tid & 63;
    int lane15 = lane & 15;
    int quad   = lane >> 4;
    int wave_m = (wid >> 1) * 64;
    int wave_n = (wid & 1) * 64;

    // A staging chunk map: chunk c -> row m=c>>2, slot cp=c&3, global k-chunk
    // q = cp ^ ((m>>1)&3)  (XOR swizzle -> 2-way-free LDS access)
    int cA0 = tid, cA1 = tid + 256;
    int mA0 = cA0 >> 2, cp0 = cA0 & 3, q0 = cp0 ^ ((mA0 >> 1) & 3);
    int mA1 = cA1 >> 2, cp1 = cA1 & 3, q1 = cp1 ^ ((mA1 >> 1) & 3);

    // fp32 A source: 8 floats per chunk (two float4), row stride S_ floats
    const char* gA0 = (const char*)(s + (size_t)(m0 + mA0) * S_ + q0 * 8);
    const char* gA1 = (const char*)(s + (size_t)(m0 + mA1) * S_ + q1 * 8);
    char* lwA0 = (char*)smemA + cA0 * 16;   // buf0 write addr; buf1 = +8192
    char* lwA1 = (char*)smemA + cA1 * 16;

    // A fragment read offsets within a buffer (in shorts)
    int aOff[4];
#pragma unroll
    for (int ss = 0; ss < 4; ss++) {
        int ml = wave_m + ss * 16 + lane15;
        aOff[ss] = ml * 32 + (quad ^ ((ml >> 1) & 3)) * 8;
    }
    // B fragment global pointers: row n, cols k0+quad*8 (.. +8)
    const char* gBf[4];
#pragma unroll
    for (int ss = 0; ss < 4; ss++) {
        int n_g = n0 + wave_n + ss * 16 + lane15;
        gBf[ss] = (const char*)(W1T + (size_t)n_g * S_ + quad * 8);
    }

    float4v acc[4][4] = {};
    // A register staging: [set] arrays, constant indices only (R4/R5 lesson:
    // dynamic indices demote to scratch)
    float4v A0lo[2], A0hi[2], A1lo[2], A1hi[2];
    short8  bfE[4], bfO[4];              // B direct-global, distance-1 dbuf

    // ---- prologue ----
    A0lo[0] = *(const float4v*)(gA0);       A0hi[0] = *(const float4v*)(gA0 + 16);
    A1lo[0] = *(const float4v*)(gA1);       A1hi[0] = *(const float4v*)(gA1 + 16);
    A0lo[1] = *(const float4v*)(gA0 + 128); A0hi[1] = *(const float4v*)(gA0 + 144);
    A1lo[1] = *(const float4v*)(gA1 + 128); A1hi[1] = *(const float4v*)(gA1 + 144);
    *(short8*)lwA0 = pack8(A0lo[0], A0hi[0]);
    *(short8*)lwA1 = pack8(A1lo[0], A1hi[0]);
#pragma unroll
    for (int ss = 0; ss < 4; ss++) bfE[ss] = *(const short8*)(gBf[ss]);   // B k=0

    for (int k = 0; k < NITER; k += 2) {
        // ---- even sub-iter j=k: compute buf0 with bfE ----
        __syncthreads();                           // buf0 staged (lgkm only)
        if (k + 2 < NITER) {                       // A set0 <- k+2
            A0lo[0] = *(const float4v*)(gA0 + 256); A0hi[0] = *(const float4v*)(gA0 + 272);
            A1lo[0] = *(const float4v*)(gA1 + 256); A1hi[0] = *(const float4v*)(gA1 + 272);
        }
        *(short8*)(lwA0 + 8192) = pack8(A0lo[1], A0hi[1]);   // set1 (k+1) -> buf1
        *(short8*)(lwA1 + 8192) = pack8(A1lo[1], A1hi[1]);
#pragma unroll
        for (int ss = 0; ss < 4; ss++) bfO[ss] = *(const short8*)(gBf[ss] + 64);  // B k+1
        {
            short8 af[4];
#pragma unroll
            for (int ss = 0; ss < 4; ss++) af[ss] = *(const short8*)(smemA + aOff[ss]);
#pragma unroll
            for (int i = 0; i < 4; i++)
#pragma unroll
                for (int j = 0; j < 4; j++)
                    acc[i][j] = __builtin_amdgcn_mfma_f32_16x16x32_bf16(af[i], bfE[j], acc[i][j], 0, 0, 0);
        }
        // ---- odd sub-iter j=k+1: compute buf1 with bfO ----
        __syncthreads();                           // buf1 staged
        if (k + 3 < NITER) {                       // A set1 <- k+3
            A0lo[1] = *(const float4v*)(gA0 + 384); A0hi[1] = *(const float4v*)(gA0 + 400);
            A1lo[1] = *(const float4v*)(gA1 + 384); A1hi[1] = *(const float4v*)(gA1 + 400);
        }
        if (k + 2 < NITER) {
            *(short8*)lwA0 = pack8(A0lo[0], A0hi[0]);        // set0 (k+2) -> buf0
            *(short8*)lwA1 = pack8(A1lo[0], A1hi[0]);
#pragma unroll
            for (int ss = 0; ss < 4; ss++) bfE[ss] = *(const short8*)(gBf[ss] + 128);  // B k+2
        }
        gA0 += 256; gA1 += 256;                    // 2 iters x 32 floats
#pragma unroll
        for (int ss = 0; ss < 4; ss++) gBf[ss] += 128;       // 2 iters x 32 shorts
        {
            short8 af[4];
#pragma unroll
            for (int ss = 0; ss < 4; ss++) af[ss] = *(const short8*)(smemA + 4096 + aOff[ss]);
#pragma unroll
            for (int i = 0; i < 4; i++)
#pragma unroll
                for (int j = 0; j < 4; j++)
                    acc[i][j] = __builtin_amdgcn_mfma_f32_16x16x32_bf16(af[i], bfO[j], acc[i][j], 0, 0, 0);
        }
    }

    // ---- fused epilogue: relu(h) @ W2[:,0:4], shuffle-reduce, atomicAdd ----
    float4v w2r[4];
    float   b1v[4];
#pragma unroll
    for (int ns = 0; ns < 4; ns++) {
        int n_g = n0 + wave_n + ns * 16 + lane15;
        w2r[ns] = *(const float4v*)(W2 + (size_t)n_g * 32);
        b1v[ns] = b1[n_g];
    }
#pragma unroll
    for (int ms = 0; ms < 4; ms++) {
        float p[4][4];
#pragma unroll
        for (int rr = 0; rr < 4; rr++)
#pragma unroll
            for (int c = 0; c < 4; c++) p[rr][c] = 0.f;
#pragma unroll
        for (int ns = 0; ns < 4; ns++) {
            float4v av = acc[ms][ns];
#pragma unroll
            for (int rr = 0; rr < 4; rr++) {
                float h = av[rr] + b1v[ns];
                h = h > 0.f ? h : 0.f;
                p[rr][0] += h * w2r[ns][0];
                p[rr][1] += h * w2r[ns][1];
                p[rr][2] += h * w2r[ns][2];
                p[rr][3] += h * w2r[ns][3];
            }
        }
#pragma unroll
        for (int off = 1; off < 16; off <<= 1)
#pragma unroll
            for (int rr = 0; rr < 4; rr++)
#pragma unroll
                for (int c = 0; c < 4; c++)
                    p[rr][c] += __shfl_xor(p[rr][c], off);
        if (lane15 < 4) {
            int c = lane15;
#pragma unroll
            for (int rr = 0; rr < 4; rr++) {
                int mg = m0 + wave_m + ms * 16 + quad * 4 + rr;
                atomicAdd(&zbuf[(size_t)mg * 4 + c], p[rr][c]);
            }
        }
    }
}

// ---- log-softmax gather + masked sum straight into d_out (zeroed beforehand) ----
__global__ __launch_bounds__(128) void reduce_logp_kernel(
        const float* __restrict__ zbuf,
        const int*   __restrict__ actions,
        const int*   __restrict__ lengths,
        const float* __restrict__ b2,
        float*       __restrict__ out)
{
    int b = blockIdx.x;
    int t = blockIdx.y * 128 + threadIdx.x;
    int len = lengths[b];
    float local = 0.f;
    if (t < MAXT && t < len) {
        int row = b * TP1 + t;
        float4v z = *(const float4v*)(zbuf + (size_t)row * 4);
        float z0 = z[0] + b2[0], z1 = z[1] + b2[1], z2 = z[2] + b2[2], z3 = z[3] + b2[3];
        float mx = fmaxf(fmaxf(z0, z1), fmaxf(z2, z3));
        float se = expf(z0 - mx) + expf(z1 - mx) + expf(z2 - mx) + expf(z3 - mx);
        int a = actions[b * MAXT + t];
        float za = (a == 0) ? z0 : (a == 1) ? z1 : (a == 2) ? z2 : z3;
        local = (za - mx) - logf(se);
    }
#pragma unroll
    for (int off = 32; off > 0; off >>= 1) local += __shfl_xor(local, off);
    __shared__ float wsum[2];
    if ((threadIdx.x & 63) == 0) wsum[threadIdx.x >> 6] = local;
    __syncthreads();
    if (threadIdx.x == 0) atomicAdd(out, -(wsum[0] + wsum[1]));   // out = -sum(logp)
}

extern "C" void kernel_launch(void* const* d_in, const int* in_sizes, int n_in,
                              void* d_out, int out_size, void* d_ws, size_t ws_size,
                              hipStream_t stream) {
    const float* s       = (const float*)d_in[0];  // (64,512,1024) fp32
    const int*   actions = (const int*)  d_in[1];  // (64,511)
    const int*   lengths = (const int*)  d_in[2];  // (64,)
    const float* W1      = (const float*)d_in[3];  // (1024,4096)
    const float* b1      = (const float*)d_in[4];  // (4096,)
    const float* W2      = (const float*)d_in[5];  // (4096,32)
    const float* b2      = (const float*)d_in[6];  // (32,)

    char* ws = (char*)d_ws;
    float*          zbuf = (float*)ws;             // [0, 512KB)
    unsigned short* W1T  = (unsigned short*)(ws + W1T_OFF);

    // zero z-buffer and output accumulator (ws/out poisoned 0xAA before every launch)
    hipMemsetAsync(ws, 0, ZBUF_BYTES, stream);
    hipMemsetAsync(d_out, 0, sizeof(float), stream);

    // pre-pass: W1 -> W1T bf16 (64x64 tiles) -- tiny now
    prep_kernel<<<dim3(1024), 256, 0, stream>>>(W1, W1T);
    // fused GEMM (A fp32 direct + in-register cvt) + relu + W2[:,0:4] projection
    gemm_fused_kernel<<<dim3(8192), 256, 0, stream>>>(s, W1T, b1, W2, lengths, zbuf);
    // log-softmax gather + masked sum -> d_out
    reduce_logp_kernel<<<dim3(B_, 4), 128, 0, stream>>>(zbuf, actions, lengths, b2, (float*)d_out);
}